// Round 1
// baseline (1160.365 us; speedup 1.0000x reference)
//
#include <hip/hip_runtime.h>

// Problem constants (from reference setup_inputs)
#define N_NODES 50000
#define N_EDGES 400000
#define HID     200
#define NCLS    10

// ---------------------------------------------------------------------------
// Kernel 1: zero the h accumulator in workspace (N_NODES x HID floats)
// ---------------------------------------------------------------------------
__global__ void gcn_zero_kernel(float* __restrict__ h, int n4) {
    int i = blockIdx.x * blockDim.x + threadIdx.x;
    if (i < n4) {
        reinterpret_cast<float4*>(h)[i] = make_float4(0.f, 0.f, 0.f, 0.f);
    }
}

// ---------------------------------------------------------------------------
// Kernel 2: edge-parallel scatter  h[row] += W0[col] * val
// 50 threads per edge, each handles one float4 chunk of the 200-dim row.
// Consecutive tids -> same edge, consecutive chunks: coalesced W0 reads and
// coalesced atomics into h.
// ---------------------------------------------------------------------------
__global__ __launch_bounds__(256) void gcn_scatter_kernel(
        const int*   __restrict__ rows,
        const int*   __restrict__ cols,
        const float* __restrict__ vals,
        const float* __restrict__ W0,
        float*       __restrict__ h) {
    const int CH = HID / 4;  // 50 float4 chunks per edge
    long long tid = (long long)blockIdx.x * blockDim.x + threadIdx.x;
    long long total = (long long)N_EDGES * CH;
    if (tid >= total) return;

    int e = (int)(tid / CH);
    int c = (int)(tid % CH);

    int   r   = rows[e];
    int   col = cols[e];
    float v   = vals[e];

    float4 w = *reinterpret_cast<const float4*>(W0 + (long long)col * HID + c * 4);
    float* dst = h + (long long)r * HID + c * 4;
    atomicAdd(dst + 0, w.x * v);
    atomicAdd(dst + 1, w.y * v);
    atomicAdd(dst + 2, w.z * v);
    atomicAdd(dst + 3, w.w * v);
}

// ---------------------------------------------------------------------------
// Kernel 3: out[n] = relu(h[n]) @ W2   (W2 staged in LDS, broadcast reads)
// One thread per node; float4 loads of the h row.
// ---------------------------------------------------------------------------
__global__ __launch_bounds__(256) void gcn_out_kernel(
        const float* __restrict__ h,
        const float* __restrict__ W2,
        float*       __restrict__ out) {
    __shared__ float w2s[HID * NCLS];  // 8000 B
    for (int i = threadIdx.x; i < HID * NCLS; i += blockDim.x)
        w2s[i] = W2[i];
    __syncthreads();

    int n = blockIdx.x * blockDim.x + threadIdx.x;
    if (n >= N_NODES) return;

    float acc[NCLS];
#pragma unroll
    for (int c = 0; c < NCLS; ++c) acc[c] = 0.f;

    const float4* hrow = reinterpret_cast<const float4*>(h + (long long)n * HID);
#pragma unroll 5
    for (int i = 0; i < HID / 4; ++i) {
        float4 hv = hrow[i];
        float x0 = fmaxf(hv.x, 0.f);
        float x1 = fmaxf(hv.y, 0.f);
        float x2 = fmaxf(hv.z, 0.f);
        float x3 = fmaxf(hv.w, 0.f);
        int d = i * 4;
#pragma unroll
        for (int c = 0; c < NCLS; ++c) {
            acc[c] += x0 * w2s[(d + 0) * NCLS + c]
                    + x1 * w2s[(d + 1) * NCLS + c]
                    + x2 * w2s[(d + 2) * NCLS + c]
                    + x3 * w2s[(d + 3) * NCLS + c];
        }
    }

    float* o = out + (long long)n * NCLS;
#pragma unroll
    for (int c = 0; c < NCLS; ++c) o[c] = acc[c];
}

// ---------------------------------------------------------------------------
// Launch
// Inputs (setup_inputs order): x[0], support_rows[1], support_cols[2],
//                              support_vals[3], W0[4], W2[5]
// ---------------------------------------------------------------------------
extern "C" void kernel_launch(void* const* d_in, const int* in_sizes, int n_in,
                              void* d_out, int out_size, void* d_ws, size_t ws_size,
                              hipStream_t stream) {
    const int*   rows = (const int*)  d_in[1];
    const int*   cols = (const int*)  d_in[2];
    const float* vals = (const float*)d_in[3];
    const float* W0   = (const float*)d_in[4];
    const float* W2   = (const float*)d_in[5];
    float*       out  = (float*)d_out;
    float*       h    = (float*)d_ws;  // N_NODES*HID*4 = 40 MB scratch

    // 1) zero h
    int n4 = (N_NODES * HID) / 4;  // 2.5M float4s
    gcn_zero_kernel<<<(n4 + 255) / 256, 256, 0, stream>>>(h, n4);

    // 2) scatter-add over edges
    long long totalS = (long long)N_EDGES * (HID / 4);
    int blocksS = (int)((totalS + 255) / 256);
    gcn_scatter_kernel<<<blocksS, 256, 0, stream>>>(rows, cols, vals, W0, h);

    // 3) relu + h @ W2
    gcn_out_kernel<<<(N_NODES + 255) / 256, 256, 0, stream>>>(h, W2, out);
}

// Round 2
// 149.031 us; speedup vs baseline: 7.7860x; 7.7860x over previous
//
#include <hip/hip_runtime.h>

// Problem constants (from reference setup_inputs)
#define N_NODES 50000
#define N_EDGES 400000
#define HID     200
#define NCLS    10
#define NBLK_SCAN ((N_NODES + 255) / 256)   // 196 blocks

// ---------------------------------------------------------------------------
// CSR build: histogram -> scan -> placement (all rebuilt every call, so
// graph replay is safe: no state carried across calls).
// ---------------------------------------------------------------------------
__global__ void k_zero_deg(int* __restrict__ deg) {
    int i = blockIdx.x * 256 + threadIdx.x;
    if (i < N_NODES) deg[i] = 0;
}

__global__ void k_hist(const int* __restrict__ rows, int* __restrict__ deg) {
    int e = blockIdx.x * 256 + threadIdx.x;
    if (e < N_EDGES) atomicAdd(&deg[rows[e]], 1);
}

// Per-block inclusive scan (Hillis-Steele in LDS); offs[g+1] = block-local
// inclusive sum; bsum[b] = block total.
__global__ void k_scan1(const int* __restrict__ deg, int* __restrict__ offs,
                        int* __restrict__ bsum) {
    __shared__ int s[256];
    int t = threadIdx.x, g = blockIdx.x * 256 + t;
    int v = (g < N_NODES) ? deg[g] : 0;
    s[t] = v;
    __syncthreads();
#pragma unroll
    for (int d = 1; d < 256; d <<= 1) {
        int x = (t >= d) ? s[t - d] : 0;
        __syncthreads();
        s[t] += x;
        __syncthreads();
    }
    if (g < N_NODES) offs[g + 1] = s[t];
    if (t == 255) bsum[blockIdx.x] = s[255];
}

// Exclusive scan of the 196 block sums (single block).
__global__ void k_scan2(int* __restrict__ bsum) {
    __shared__ int s[256];
    int t = threadIdx.x;
    int v = (t < NBLK_SCAN) ? bsum[t] : 0;
    s[t] = v;
    __syncthreads();
#pragma unroll
    for (int d = 1; d < 256; d <<= 1) {
        int x = (t >= d) ? s[t - d] : 0;
        __syncthreads();
        s[t] += x;
        __syncthreads();
    }
    bsum[t] = s[t] - v;  // exclusive
}

__global__ void k_scan3(int* __restrict__ offs, const int* __restrict__ bsum) {
    int g = blockIdx.x * 256 + threadIdx.x;
    if (g < N_NODES) offs[g + 1] += bsum[blockIdx.x];
    if (g == 0) offs[0] = 0;
}

// Place edges into CSR order. atomicAdd on offs[r] doubles as the cursor;
// afterwards offs[r] == end(r), and start(r) = end(r) - deg[r].
__global__ void k_place(const int* __restrict__ rows, const int* __restrict__ cols,
                        const float* __restrict__ vals,
                        int* offs, int* __restrict__ col_s, float* __restrict__ val_s) {
    int e = blockIdx.x * 256 + threadIdx.x;
    if (e >= N_EDGES) return;
    int r = rows[e];
    int pos = atomicAdd(&offs[r], 1);
    col_s[pos] = cols[e];
    val_s[pos] = vals[e];
}

// ---------------------------------------------------------------------------
// Fused SpMM + ReLU + (h @ W2): one wave per row (grid-stride over rows).
// Lane owns dims d = lane + 64k (k=0..3, d<200). W2 fragments live in
// registers (loaded once per wave, reused across rows). Wave-reduce the 10
// output channels with __shfl_xor; lane 0 writes them.
// ---------------------------------------------------------------------------
__global__ __launch_bounds__(256) void gcn_fused(
        const int*   __restrict__ deg,
        const int*   __restrict__ offs_end,   // post-placement offs: end(r)
        const int*   __restrict__ col_s,
        const float* __restrict__ val_s,
        const float* __restrict__ W0,
        const float* __restrict__ W2,
        float*       __restrict__ out) {
    int lane = threadIdx.x & 63;
    int wid  = (blockIdx.x * blockDim.x + threadIdx.x) >> 6;  // global wave id
    int nwaves = (gridDim.x * blockDim.x) >> 6;

    // Register-resident W2 fragment for this lane's dims (zero for d>=HID).
    float w2r[4][NCLS];
#pragma unroll
    for (int k = 0; k < 4; ++k) {
        int d = lane + 64 * k;
#pragma unroll
        for (int c = 0; c < NCLS; ++c)
            w2r[k][c] = (d < HID) ? W2[d * NCLS + c] : 0.f;
    }

    for (int r = wid; r < N_NODES; r += nwaves) {
        int end   = offs_end[r];
        int start = end - deg[r];

        float hk[4] = {0.f, 0.f, 0.f, 0.f};
        for (int e = start; e < end; ++e) {
            int   col = col_s[e];
            float v   = val_s[e];
            const float* wrow = W0 + (long long)col * HID;
#pragma unroll
            for (int k = 0; k < 4; ++k) {
                int d = lane + 64 * k;
                if (d < HID) hk[k] += v * wrow[d];
            }
        }

        float acc[NCLS];
#pragma unroll
        for (int c = 0; c < NCLS; ++c) acc[c] = 0.f;
#pragma unroll
        for (int k = 0; k < 4; ++k) {
            float x = fmaxf(hk[k], 0.f);
#pragma unroll
            for (int c = 0; c < NCLS; ++c) acc[c] += x * w2r[k][c];
        }

        // 64-lane butterfly reduction of the 10 channel sums.
#pragma unroll
        for (int c = 0; c < NCLS; ++c) {
#pragma unroll
            for (int off = 32; off >= 1; off >>= 1)
                acc[c] += __shfl_xor(acc[c], off, 64);
        }

        if (lane == 0) {
#pragma unroll
            for (int c = 0; c < NCLS; ++c)
                out[(long long)r * NCLS + c] = acc[c];
        }
    }
}

// ---------------------------------------------------------------------------
// Launch. Inputs: x[0], support_rows[1], support_cols[2], support_vals[3],
//                 W0[4], W2[5]
// ws layout (bytes): deg @0 (200000), offs @200064 (200004), bsum @400128
// (1024), col_s @401408 (1.6M), val_s @2001408 (1.6M). Total ~3.6 MB.
// ---------------------------------------------------------------------------
extern "C" void kernel_launch(void* const* d_in, const int* in_sizes, int n_in,
                              void* d_out, int out_size, void* d_ws, size_t ws_size,
                              hipStream_t stream) {
    const int*   rows = (const int*)  d_in[1];
    const int*   cols = (const int*)  d_in[2];
    const float* vals = (const float*)d_in[3];
    const float* W0   = (const float*)d_in[4];
    const float* W2   = (const float*)d_in[5];
    float*       out  = (float*)d_out;

    char* ws = (char*)d_ws;
    int*   deg   = (int*)  (ws);
    int*   offs  = (int*)  (ws + 200064);
    int*   bsum  = (int*)  (ws + 400128);
    int*   col_s = (int*)  (ws + 401408);
    float* val_s = (float*)(ws + 2001408);

    int blocksN = (N_NODES + 255) / 256;  // 196
    int blocksE = (N_EDGES + 255) / 256;  // 1563

    k_zero_deg<<<blocksN, 256, 0, stream>>>(deg);
    k_hist   <<<blocksE, 256, 0, stream>>>(rows, deg);
    k_scan1  <<<blocksN, 256, 0, stream>>>(deg, offs, bsum);
    k_scan2  <<<1,       256, 0, stream>>>(bsum);
    k_scan3  <<<blocksN, 256, 0, stream>>>(offs, bsum);
    k_place  <<<blocksE, 256, 0, stream>>>(rows, cols, vals, offs, col_s, val_s);

    // 4096 blocks * 4 waves = 16384 waves; ~3-4 rows per wave.
    gcn_fused<<<4096, 256, 0, stream>>>(deg, offs, col_s, val_s, W0, W2, out);
}

// Round 3
// 124.812 us; speedup vs baseline: 9.2969x; 1.1940x over previous
//
#include <hip/hip_runtime.h>

// Problem constants (from reference setup_inputs)
#define N_NODES 50000
#define N_EDGES 400000
#define HID     200
#define NCLS    10

// ws layout (bytes):
//   deg   @ 0        (50000*4 = 200000)
//   gcnt  @ 200000   (4; zeroed together with deg)
//   start @ 200064   (200000)
//   cur   @ 400128   (200000)
//   col_s @ 600192   (1600000)
//   val_s @ 2200192  (1600000)

// ---------------------------------------------------------------------------
// Zero deg + gcnt (one kernel).
// ---------------------------------------------------------------------------
__global__ void k_zero(int* __restrict__ deg_and_cnt) {
    int i = blockIdx.x * 256 + threadIdx.x;
    if (i <= N_NODES) deg_and_cnt[i] = 0;   // deg[0..N-1] and gcnt at [N]
}

__global__ void k_hist(const int* __restrict__ rows, int* __restrict__ deg) {
    int e = blockIdx.x * 256 + threadIdx.x;
    if (e < N_EDGES) atomicAdd(&deg[rows[e]], 1);
}

// ---------------------------------------------------------------------------
// Segment allocation without a global scan: wave-level inclusive scan of
// degrees + one atomicAdd per wave on a global cursor. Segments are disjoint
// and contiguous (order across rows is irrelevant for correctness).
// ---------------------------------------------------------------------------
__global__ __launch_bounds__(256) void k_alloc(const int* __restrict__ deg,
                                               int* __restrict__ start_,
                                               int* __restrict__ cur,
                                               int* __restrict__ gcnt) {
    int r = blockIdx.x * 256 + threadIdx.x;
    int lane = threadIdx.x & 63;
    int d = (r < N_NODES) ? deg[r] : 0;
    int incl = d;
#pragma unroll
    for (int off = 1; off < 64; off <<= 1) {
        int x = __shfl_up(incl, off, 64);
        incl += (lane >= off) ? x : 0;
    }
    int wtot = __shfl(incl, 63, 64);
    int base = 0;
    if (lane == 0) base = atomicAdd(gcnt, wtot);
    base = __shfl(base, 0, 64);
    int st = base + incl - d;
    if (r < N_NODES) { start_[r] = st; cur[r] = st; }
}

__global__ void k_place(const int* __restrict__ rows, const int* __restrict__ cols,
                        const float* __restrict__ vals,
                        int* __restrict__ cur,
                        int* __restrict__ col_s, float* __restrict__ val_s) {
    int e = blockIdx.x * 256 + threadIdx.x;
    if (e >= N_EDGES) return;
    int r = rows[e];
    int pos = atomicAdd(&cur[r], 1);
    col_s[pos] = cols[e];
    val_s[pos] = vals[e];
}

// ---------------------------------------------------------------------------
// Fused SpMM + ReLU + (h @ W2). One wave per row (grid-stride).
// Lane l (<50) owns dims [4l, 4l+3]: one dwordx4 gather per edge per lane.
// Edge loop unrolled x4 -> 4 independent 16B gathers in flight per lane.
// W2 staged in LDS, per-lane rows, pitch 41 (odd stride -> conflict-free);
// rows for lanes 50..63 are zero so their (duplicated) hk contributes 0.
// ---------------------------------------------------------------------------
__global__ __launch_bounds__(256) void gcn_fused(
        const int*   __restrict__ deg,
        const int*   __restrict__ start_,
        const int*   __restrict__ col_s,
        const float* __restrict__ val_s,
        const float* __restrict__ W0,
        const float* __restrict__ W2,
        float*       __restrict__ out) {
    __shared__ float w2t[64 * 41];   // 10496 B

    for (int i = threadIdx.x; i < 64 * 41; i += 256) w2t[i] = 0.f;
    __syncthreads();
    // w2t[l*41 + (j*10+c)] = W2[(4l+j)*10 + c] = W2[l*40 + (j*10+c)]
    for (int i = threadIdx.x; i < HID * NCLS; i += 256) {
        int l = i / 40, rem = i - l * 40;
        w2t[l * 41 + rem] = W2[i];
    }
    __syncthreads();

    const int lane = threadIdx.x & 63;
    const int off4 = 4 * (lane < 50 ? lane : 49);   // clamp: lanes 50-63 duplicate lane 49 (safe reads)
    const float* __restrict__ w2l = &w2t[lane * 41];

    int wid = (blockIdx.x * blockDim.x + threadIdx.x) >> 6;
    int nw  = (gridDim.x * blockDim.x) >> 6;

    for (int r = wid; r < N_NODES; r += nw) {
        int st  = start_[r];
        int dg  = deg[r];
        int end = st + dg;

        float4 hk = make_float4(0.f, 0.f, 0.f, 0.f);
        int e = st;
        for (; e + 4 <= end; e += 4) {
            int   c0 = col_s[e + 0]; float v0 = val_s[e + 0];
            int   c1 = col_s[e + 1]; float v1 = val_s[e + 1];
            int   c2 = col_s[e + 2]; float v2 = val_s[e + 2];
            int   c3 = col_s[e + 3]; float v3 = val_s[e + 3];
            float4 a = *reinterpret_cast<const float4*>(W0 + (size_t)c0 * HID + off4);
            float4 b = *reinterpret_cast<const float4*>(W0 + (size_t)c1 * HID + off4);
            float4 c = *reinterpret_cast<const float4*>(W0 + (size_t)c2 * HID + off4);
            float4 d = *reinterpret_cast<const float4*>(W0 + (size_t)c3 * HID + off4);
            hk.x += v0 * a.x + v1 * b.x + v2 * c.x + v3 * d.x;
            hk.y += v0 * a.y + v1 * b.y + v2 * c.y + v3 * d.y;
            hk.z += v0 * a.z + v1 * b.z + v2 * c.z + v3 * d.z;
            hk.w += v0 * a.w + v1 * b.w + v2 * c.w + v3 * d.w;
        }
        for (; e < end; ++e) {
            int   c0 = col_s[e]; float v0 = val_s[e];
            float4 a = *reinterpret_cast<const float4*>(W0 + (size_t)c0 * HID + off4);
            hk.x += v0 * a.x; hk.y += v0 * a.y; hk.z += v0 * a.z; hk.w += v0 * a.w;
        }

        float x0 = fmaxf(hk.x, 0.f);
        float x1 = fmaxf(hk.y, 0.f);
        float x2 = fmaxf(hk.z, 0.f);
        float x3 = fmaxf(hk.w, 0.f);

        float acc[NCLS];
#pragma unroll
        for (int c = 0; c < NCLS; ++c) {
            acc[c] = x0 * w2l[0 * NCLS + c] + x1 * w2l[1 * NCLS + c]
                   + x2 * w2l[2 * NCLS + c] + x3 * w2l[3 * NCLS + c];
        }

#pragma unroll
        for (int c = 0; c < NCLS; ++c) {
#pragma unroll
            for (int off = 32; off >= 1; off >>= 1)
                acc[c] += __shfl_xor(acc[c], off, 64);
        }

        if (lane == 0) {
            float* o = out + (size_t)r * NCLS;
#pragma unroll
            for (int c = 0; c < NCLS; c += 2) {
                float2 p = make_float2(acc[c], acc[c + 1]);
                *reinterpret_cast<float2*>(o + c) = p;   // out rows are 8B-aligned
            }
        }
    }
}

// ---------------------------------------------------------------------------
// Launch. Inputs: x[0], support_rows[1], support_cols[2], support_vals[3],
//                 W0[4], W2[5]
// ---------------------------------------------------------------------------
extern "C" void kernel_launch(void* const* d_in, const int* in_sizes, int n_in,
                              void* d_out, int out_size, void* d_ws, size_t ws_size,
                              hipStream_t stream) {
    const int*   rows = (const int*)  d_in[1];
    const int*   cols = (const int*)  d_in[2];
    const float* vals = (const float*)d_in[3];
    const float* W0   = (const float*)d_in[4];
    const float* W2   = (const float*)d_in[5];
    float*       out  = (float*)d_out;

    char* ws = (char*)d_ws;
    int*   deg   = (int*)  (ws);            // also covers gcnt at [N_NODES]
    int*   gcnt  = (int*)  (ws + 200000);
    int*   start_= (int*)  (ws + 200064);
    int*   cur   = (int*)  (ws + 400128);
    int*   col_s = (int*)  (ws + 600192);
    float* val_s = (float*)(ws + 2200192);

    int blocksN = (N_NODES + 256) / 256;   // covers N_NODES+1 entries (deg+gcnt)
    int blocksE = (N_EDGES + 255) / 256;

    k_zero <<<blocksN, 256, 0, stream>>>(deg);
    k_hist <<<blocksE, 256, 0, stream>>>(rows, deg);
    k_alloc<<<(N_NODES + 255) / 256, 256, 0, stream>>>(deg, start_, cur, gcnt);
    k_place<<<blocksE, 256, 0, stream>>>(rows, cols, vals, cur, col_s, val_s);

    gcn_fused<<<4096, 256, 0, stream>>>(deg, start_, col_s, val_s, W0, W2, out);
}